// Round 1
// 399.944 us; speedup vs baseline: 1.0015x; 1.0015x over previous
//
#include <hip/hip_runtime.h>
#include <cfloat>

#define N_NODES 50000
#define N_EDGES 1600000
#define DX      128
#define DH      64
#define KH      4
#define NC      256                   // KH*DH
#define NEG_SLOPE 0.01f
#define SCAN_BLOCKS 196               // bucket count (dst>>8)
#define BIN_BLOCKS 250
#define BIN_CHUNK  6400               // 250*6400 = 1.6M edges exactly

typedef float f2 __attribute__((ext_vector_type(2)));

// ---------- setup: zero bcnt/colsum, transpose Ww (256x128)->Wt(128x256) ----------
__global__ void k_setup(const float* __restrict__ Ww, float* __restrict__ Wt,
                        int* __restrict__ bcnt, float* __restrict__ colsum) {
    int i = blockIdx.x * 256 + threadIdx.x;   // grid 128 -> 32768 threads
    if (i < SCAN_BLOCKS) bcnt[i] = 0;
    if (i < NC) colsum[i] = 0.f;
    {
        int d = i >> 8, c = i & 255;
        Wt[d * NC + c] = Ww[c * DX + d];
    }
}

__device__ __forceinline__ unsigned pack_bf16(float a, float b) {
    unsigned ua = __float_as_uint(a), ub = __float_as_uint(b);
    ua = (ua + 0x7FFFu + ((ua >> 16) & 1u)) >> 16;          // RNE
    ub = (ub + 0x7FFFu + ((ub >> 16) & 1u)) & 0xFFFF0000u;
    return ua | ub;
}

// ---------- Wx GEMM + fused si/sj epilogue; writes bf16 copy for the gather ----------
__global__ void __launch_bounds__(256) k_gemm1(const float* __restrict__ x,
                                               const float* __restrict__ Wt,
                                               const float* __restrict__ Wb,
                                               const float* __restrict__ aw,
                                               const float* __restrict__ ab,
                                               uint2* __restrict__ Wxb,
                                               float* __restrict__ sic,
                                               float* __restrict__ sjc) {
    int wave = blockIdx.x * 4 + __builtin_amdgcn_readfirstlane(threadIdx.x >> 6);
    if (wave >= N_NODES / 8) return;           // 50000 % 8 == 0
    int lane = threadIdx.x & 63;
    int kh = lane >> 4, lq = lane & 15;
    int n0 = wave * 8;
    const float4* WtV = (const float4*)Wt;
    float acc[8][4];
#pragma unroll
    for (int r = 0; r < 8; ++r)
#pragma unroll
        for (int q = 0; q < 4; ++q) acc[r][q] = 0.f;

    for (int d = 0; d < DX; d += 4) {
        float xr[8][4];
#pragma unroll
        for (int r = 0; r < 8; ++r) {
            float4 v = *(const float4*)&x[(size_t)(n0 + r) * DX + d];
            xr[r][0] = v.x; xr[r][1] = v.y; xr[r][2] = v.z; xr[r][3] = v.w;
        }
#pragma unroll
        for (int q = 0; q < 4; ++q) {
            float4 wv = WtV[(size_t)(d + q) * 64 + lane];
#pragma unroll
            for (int r = 0; r < 8; ++r) {
                acc[r][0] += xr[r][q] * wv.x;
                acc[r][1] += xr[r][q] * wv.y;
                acc[r][2] += xr[r][q] * wv.z;
                acc[r][3] += xr[r][q] * wv.w;
            }
        }
    }
    float4 bias = ((const float4*)Wb)[lane];
    const float* awi = aw + kh * 2 * DH + lq * 4;
    const float* awj = awi + DH;
    float ai0 = awi[0], ai1 = awi[1], ai2 = awi[2], ai3 = awi[3];
    float aj0 = awj[0], aj1 = awj[1], aj2 = awj[2], aj3 = awj[3];
    float abk = ab[kh];
#pragma unroll
    for (int r = 0; r < 8; ++r) {
        float o0 = acc[r][0] + bias.x, o1 = acc[r][1] + bias.y;
        float o2 = acc[r][2] + bias.z, o3 = acc[r][3] + bias.w;
        uint2 pk; pk.x = pack_bf16(o0, o1); pk.y = pack_bf16(o2, o3);
        Wxb[(size_t)(n0 + r) * 64 + lane] = pk;
        float pi = o0 * ai0 + o1 * ai1 + o2 * ai2 + o3 * ai3;
        float pj = o0 * aj0 + o1 * aj1 + o2 * aj2 + o3 * aj3;
#pragma unroll
        for (int off = 8; off >= 1; off >>= 1) {
            pi += __shfl_xor(pi, off, 64);
            pj += __shfl_xor(pj, off, 64);
        }
        if (lq == 0) {
            sic[(n0 + r) * 4 + kh] = pi + abk;   // fold ab into dst-side score
            sjc[(n0 + r) * 4 + kh] = pj;
        }
    }
}

// ---------- bucket histogram: 196 bins, LDS-aggregated ----------
__global__ void __launch_bounds__(256) k_bhist(const int* __restrict__ ei,
                                               int* __restrict__ bcnt) {
    __shared__ int bh[SCAN_BLOCKS];
    int t = threadIdx.x;
    if (t < SCAN_BLOCKS) bh[t] = 0;
    __syncthreads();
    int e0 = blockIdx.x * BIN_CHUNK;
#pragma unroll 5
    for (int k = 0; k < BIN_CHUNK / 256; ++k) {
        int dst = ei[N_EDGES + e0 + t + k * 256];
        atomicAdd(&bh[dst >> 8], 1);
    }
    __syncthreads();
    if (t < SCAN_BLOCKS) atomicAdd(&bcnt[t], bh[t]);
}

// ---------- scan 196 bucket counts -> bbase (exclusive) + bcur ----------
__global__ void __launch_bounds__(256) k_scanb(const int* __restrict__ bcnt,
                                               int* __restrict__ bbase,
                                               int* __restrict__ bcur) {
    __shared__ int s[256];
    int t = threadIdx.x;
    int v = (t < SCAN_BLOCKS) ? bcnt[t] : 0;
    s[t] = v;
    __syncthreads();
#pragma unroll
    for (int off = 1; off < 256; off <<= 1) {
        int u = (t >= off) ? s[t - off] : 0;
        __syncthreads();
        s[t] += u;
        __syncthreads();
    }
    if (t < SCAN_BLOCKS) {
        int ex = s[t] - v;
        bbase[t] = ex;
        bcur[t] = ex;
    }
    if (t == SCAN_BLOCKS - 1) bbase[SCAN_BLOCKS] = s[t];   // = N_EDGES
}

// ---------- binning pass: edges -> 196 dst-buckets, dense chunked writes ----------
__global__ void __launch_bounds__(256) k_bin(const int* __restrict__ ei,
                                             int* __restrict__ bcur,
                                             unsigned* __restrict__ binned) {
    __shared__ int bh[SCAN_BLOCKS];   // count, then local cursor
    __shared__ int bb[SCAN_BLOCKS];   // reserved global base
    int t = threadIdx.x;
    if (t < SCAN_BLOCKS) bh[t] = 0;
    __syncthreads();
    int e0 = blockIdx.x * BIN_CHUNK;
#pragma unroll 5
    for (int k = 0; k < BIN_CHUNK / 256; ++k) {
        int dst = ei[N_EDGES + e0 + t + k * 256];
        atomicAdd(&bh[dst >> 8], 1);
    }
    __syncthreads();
    if (t < SCAN_BLOCKS) {
        bb[t] = atomicAdd(&bcur[t], bh[t]);
        bh[t] = 0;
    }
    __syncthreads();
#pragma unroll 5
    for (int k = 0; k < BIN_CHUNK / 256; ++k) {
        int e = e0 + t + k * 256;
        int src = ei[e];
        int dst = ei[N_EDGES + e];
        int b = dst >> 8;
        int lo = atomicAdd(&bh[b], 1);
        binned[bb[b] + lo] = (unsigned)src | ((unsigned)(dst & 255) << 16);   // src < 2^16
    }
}

// ---------- fused per-bucket: count dsts + scan + rowstart + self-loop + scatter ----------
__global__ void __launch_bounds__(256) k_scatter3(const unsigned* __restrict__ binned,
                                                  const int* __restrict__ bbase,
                                                  int* __restrict__ rowstart,
                                                  int* __restrict__ csr_src) {
    __shared__ int lcnt[256];
    __shared__ int lcur[256];
    __shared__ int s[256];
    int t = threadIdx.x, b = blockIdx.x;
    int e0 = bbase[b], e1 = bbase[b + 1];
    lcnt[t] = 0;
    __syncthreads();
    for (int i = e0 + t; i < e1; i += 256)
        atomicAdd(&lcnt[binned[i] >> 16], 1);
    __syncthreads();
    int v = lcnt[t];
    s[t] = v;
    __syncthreads();
#pragma unroll
    for (int off = 1; off < 256; off <<= 1) {
        int u = (t >= off) ? s[t - off] : 0;
        __syncthreads();
        s[t] += u;
        __syncthreads();
    }
    int d = b * 256 + t;
    int base_b = e0 + 256 * b;              // edges before bucket + self-loops before bucket
    if (d < N_NODES) {
        int rs = base_b + (s[t] - v) + t;   // + t self-loops within bucket
        rowstart[d] = rs;
        csr_src[rs] = d;                    // self-loop edge placed first
        lcur[t] = rs + 1;
    } else lcur[t] = 0;
    if (b == 0 && t == 0) rowstart[N_NODES] = N_EDGES + N_NODES;
    __syncthreads();
    for (int i = e0 + t; i < e1; i += 256) {
        unsigned u = binned[i];
        int pos = atomicAdd(&lcur[u >> 16], 1);
        csr_src[pos] = (int)(u & 0xFFFFu);
    }
}

// ---------- aggregation, two-phase:
//   phase A: lane==edge, computes ex for all 4 heads + den partials, stores
//            duplicated pairs to wave-private LDS.
//   phase B: lean accumulate — readlane(src)->SGPR base (scalar addr math),
//            ds_read_b64 broadcast ex pair, packed-f32 FMAs. ----------
__device__ __forceinline__ void acc_edge(uint2 g, f2 ev, f2& a01, f2& a23) {
    f2 w01, w23;
    w01.x = __uint_as_float(g.x << 16);
    w01.y = __uint_as_float(g.x & 0xFFFF0000u);
    w23.x = __uint_as_float(g.y << 16);
    w23.y = __uint_as_float(g.y & 0xFFFF0000u);
    a01 = __builtin_elementwise_fma(w01, ev, a01);
    a23 = __builtin_elementwise_fma(w23, ev, a23);
}

__global__ void __launch_bounds__(256) k_aggregate(const int* __restrict__ rowstart,
                                                   const int* __restrict__ csr_src,
                                                   const float* __restrict__ sic,
                                                   const float* __restrict__ sjc,
                                                   const uint2* __restrict__ Wxb,
                                                   uint2* __restrict__ expb) {
    __shared__ float exls[4][64 * 8];                 // per-wave: 64 edges x 4 heads, duplicated pairs
    int wv = threadIdx.x >> 6;
    int dst = blockIdx.x * 4 + wv;                    // grid = 12500, exact
    int lane = threadIdx.x & 63;
    int kh = lane >> 4;
    int i0 = rowstart[dst], i1 = rowstart[dst + 1];
    float4 si = *(const float4*)&sic[(size_t)dst * 4];   // broadcast (ab folded into sic)
    float* exl = exls[wv];
    const float* exb = exl + kh * 2;
    const char* wxp = (const char*)Wxb;
    size_t loff = (size_t)lane * 8;

    f2 acc01 = {0.f, 0.f}, acc23 = {0.f, 0.f};
    float den0 = 0.f, den1 = 0.f, den2 = 0.f, den3 = 0.f;

    for (int b = i0; b < i1; b += 64) {
        int cnt = i1 - b;
        if (cnt > 64) cnt = 64;
        // ---- phase A: one edge per lane ----
        int idx = b + lane;
        if (lane >= cnt) idx = i1 - 1;
        int sl = csr_src[idx];
        float ex0 = 0.f, ex1 = 0.f, ex2 = 0.f, ex3 = 0.f;
        if (lane < cnt) {
            float4 sj = *(const float4*)&sjc[(size_t)sl * 4];
            float e0 = si.x + sj.x, e1 = si.y + sj.y;
            float e2 = si.z + sj.z, e3 = si.w + sj.w;
            e0 = fmaxf(e0, NEG_SLOPE * e0);
            e1 = fmaxf(e1, NEG_SLOPE * e1);
            e2 = fmaxf(e2, NEG_SLOPE * e2);
            e3 = fmaxf(e3, NEG_SLOPE * e3);
            ex0 = __expf(e0); ex1 = __expf(e1);
            ex2 = __expf(e2); ex3 = __expf(e3);
            den0 += ex0; den1 += ex1; den2 += ex2; den3 += ex3;
        }
        *(float4*)&exl[lane * 8]     = make_float4(ex0, ex0, ex1, ex1);
        *(float4*)&exl[lane * 8 + 4] = make_float4(ex2, ex2, ex3, ex3);
        asm volatile("" ::: "memory");    // keep phase A stores before phase B reads
        // ---- phase B: lean accumulate over the batch ----
        int e = 0;
        for (; e + 8 <= cnt; e += 8) {
            int ss[8];
#pragma unroll
            for (int u = 0; u < 8; ++u) ss[u] = __builtin_amdgcn_readlane(sl, e + u);
            uint2 gg[8];
#pragma unroll
            for (int u = 0; u < 8; ++u)
                gg[u] = *(const uint2*)(wxp + (((size_t)(unsigned)ss[u]) << 9) + loff);
            f2 ee[8];
#pragma unroll
            for (int u = 0; u < 8; ++u) ee[u] = *(const f2*)&exb[(size_t)(e + u) * 8];
#pragma unroll
            for (int u = 0; u < 8; ++u) acc_edge(gg[u], ee[u], acc01, acc23);
        }
        for (; e < cnt; ++e) {
            int s = __builtin_amdgcn_readlane(sl, e);
            uint2 g = *(const uint2*)(wxp + (((size_t)(unsigned)s) << 9) + loff);
            f2 ev = *(const f2*)&exb[(size_t)e * 8];
            acc_edge(g, ev, acc01, acc23);
        }
        asm volatile("" ::: "memory");    // keep next batch's stores after these reads
    }

    // ---- den reduce: fold the 4 16-lane groups, select my head, butterfly ----
    den0 += __shfl_xor(den0, 16, 64); den0 += __shfl_xor(den0, 32, 64);
    den1 += __shfl_xor(den1, 16, 64); den1 += __shfl_xor(den1, 32, 64);
    den2 += __shfl_xor(den2, 16, 64); den2 += __shfl_xor(den2, 32, 64);
    den3 += __shfl_xor(den3, 16, 64); den3 += __shfl_xor(den3, 32, 64);
    float dsel = (kh < 2) ? ((kh == 0) ? den0 : den1) : ((kh == 2) ? den2 : den3);
    dsel += __shfl_xor(dsel, 1, 64);
    dsel += __shfl_xor(dsel, 2, 64);
    dsel += __shfl_xor(dsel, 4, 64);
    dsel += __shfl_xor(dsel, 8, 64);

    float r = 1.f / dsel;
    float o0 = __expf(acc01.x * r), o1 = __expf(acc01.y * r);
    float o2 = __expf(acc23.x * r), o3 = __expf(acc23.y * r);
    uint2 pk; pk.x = pack_bf16(o0, o1); pk.y = pack_bf16(o2, o3);
    expb[(size_t)dst * 64 + lane] = pk;          // bf16 exp(agg), cols 4l..4l+3
}

// ---------- column sums of exp(agg), bf16 input, 2 cols/thread ----------
__global__ void __launch_bounds__(256) k_colsum(const unsigned* __restrict__ expb,
                                                float* __restrict__ colsum) {
    int tid = threadIdx.x;
    int cp = tid & 127;            // uint index within row (cols 2cp, 2cp+1)
    int ro = tid >> 7;             // row parity
    int base = blockIdx.x * 196;
    int r1 = min(base + 196, N_NODES);
    float s0 = 0.f, s1 = 0.f;
    for (int r = base + ro; r < r1; r += 2) {
        unsigned u = expb[(size_t)r * 128 + cp];
        s0 += __uint_as_float(u << 16);
        s1 += __uint_as_float(u & 0xFFFF0000u);
    }
    atomicAdd(&colsum[2 * cp], s0);
    atomicAdd(&colsum[2 * cp + 1], s1);
}

// ---------- Ws[c][j] = Wo_w[j][c] / colsum[c] ----------
__global__ void k_prepWs(const float* __restrict__ Wo_w, const float* __restrict__ colsum,
                         float* __restrict__ Ws) {
    int i = blockIdx.x * 256 + threadIdx.x;   // 16384 total
    int c = i >> 6, j = i & 63;
    Ws[c * 64 + j] = Wo_w[j * NC + c] / colsum[c];
}

// ---------- out = expb @ Ws + b, LDS-tiled ----------
// j0 MUST be readfirstlane'd: makes Ws reads provably wave-uniform -> s_load.
__global__ void __launch_bounds__(256) k_out(const uint2* __restrict__ expb,
                                             const float* __restrict__ Ws,
                                             const float* __restrict__ Wo_b,
                                             float* __restrict__ out) {
    __shared__ unsigned tile[64][129];
    int n0 = blockIdx.x * 64;
    int rows = min(64, N_NODES - n0);
    int tid = threadIdx.x;

#pragma unroll
    for (int it = 0; it < 16; ++it) {
        int idx = tid + it * 256;          // 64 rows x 64 uint2
        int row = idx >> 6;                // wave-uniform per iteration
        int c4 = idx & 63;                 // lane-contiguous -> 512B bursts
        if (row < rows) {
            uint2 v = expb[(size_t)(n0 + row) * 64 + c4];
            tile[row][c4 * 2] = v.x;
            tile[row][c4 * 2 + 1] = v.y;
        }
    }
    __syncthreads();

    int nl = tid & 63;
    int j0 = __builtin_amdgcn_readfirstlane((tid >> 6) * 16);   // scalarize!
    int nr = min(nl, rows - 1);
    float acc[16];
#pragma unroll
    for (int jj = 0; jj < 16; ++jj) acc[jj] = 0.f;

#pragma unroll 2
    for (int cp = 0; cp < 128; ++cp) {     // 2 cols per iteration
        unsigned u = tile[nr][cp];
        float a0 = __uint_as_float(u << 16);
        float a1 = __uint_as_float(u & 0xFFFF0000u);
        const float* w0 = Ws + (2 * cp) * 64 + j0;   // wave-uniform -> s_load
        const float* w1 = w0 + 64;
#pragma unroll
        for (int jj = 0; jj < 16; ++jj)
            acc[jj] += a0 * w0[jj] + a1 * w1[jj];
    }

    if (nl < rows) {
        float* op = &out[(size_t)(n0 + nl) * DH + j0];
#pragma unroll
        for (int q = 0; q < 4; ++q) {
            float4 o;
            o.x = acc[q * 4 + 0] + Wo_b[j0 + q * 4 + 0];
            o.y = acc[q * 4 + 1] + Wo_b[j0 + q * 4 + 1];
            o.z = acc[q * 4 + 2] + Wo_b[j0 + q * 4 + 2];
            o.w = acc[q * 4 + 3] + Wo_b[j0 + q * 4 + 3];
            *(float4*)(op + q * 4) = o;
        }
    }
}

extern "C" void kernel_launch(void* const* d_in, const int* in_sizes, int n_in,
                              void* d_out, int out_size, void* d_ws, size_t ws_size,
                              hipStream_t stream) {
    const int*   ei   = (const int*)d_in[0];     // int32 from harness
    const float* x    = (const float*)d_in[1];
    const float* Ww   = (const float*)d_in[2];
    const float* Wb   = (const float*)d_in[3];
    const float* aw   = (const float*)d_in[4];
    const float* ab   = (const float*)d_in[5];
    const float* Wo_w = (const float*)d_in[6];
    const float* Wo_b = (const float*)d_in[7];
    float* out = (float*)d_out;

    char* p = (char*)d_ws;
    auto alloc = [&](size_t bytes) -> char* {
        char* q = p;
        p += (bytes + 255) & ~(size_t)255;
        return q;
    };
    uint2*    Wxb      = (uint2*)alloc((size_t)N_NODES * NC * 2);   // bf16 Wx copy
    uint2*    expb     = (uint2*)alloc((size_t)N_NODES * NC * 2);   // bf16 exp(agg)
    float*    Wt       = (float*)alloc((size_t)DX * NC * 4);
    float*    sic      = (float*)alloc((size_t)N_NODES * 4 * 4);
    float*    sjc      = (float*)alloc((size_t)N_NODES * 4 * 4);
    int*      rowstart = (int*)alloc((size_t)(N_NODES + 1) * 4);
    int*      csr_src  = (int*)alloc((size_t)(N_EDGES + N_NODES) * 4);
    unsigned* binned   = (unsigned*)alloc((size_t)N_EDGES * 4);
    float*    colsum   = (float*)alloc(NC * 4);
    float*    Ws       = (float*)alloc(NC * DH * 4);
    int*      bcnt     = (int*)alloc(SCAN_BLOCKS * 4);
    int*      bbase    = (int*)alloc((SCAN_BLOCKS + 1) * 4);
    int*      bcur     = (int*)alloc(SCAN_BLOCKS * 4);

    k_setup<<<128, 256, 0, stream>>>(Ww, Wt, bcnt, colsum);
    k_gemm1<<<(N_NODES / 8 + 3) / 4, 256, 0, stream>>>(x, Wt, Wb, aw, ab, Wxb, sic, sjc);
    k_bhist<<<BIN_BLOCKS, 256, 0, stream>>>(ei, bcnt);
    k_scanb<<<1, 256, 0, stream>>>(bcnt, bbase, bcur);
    k_bin<<<BIN_BLOCKS, 256, 0, stream>>>(ei, bcur, binned);
    k_scatter3<<<SCAN_BLOCKS, 256, 0, stream>>>(binned, bbase, rowstart, csr_src);
    k_aggregate<<<N_NODES / 4, 256, 0, stream>>>(rowstart, csr_src, sic, sjc, Wxb, expb);
    k_colsum<<<256, 256, 0, stream>>>((const unsigned*)expb, colsum);
    k_prepWs<<<(NC * DH) / 256, 256, 0, stream>>>(Wo_w, colsum, Ws);
    k_out<<<(N_NODES + 63) / 64, 256, 0, stream>>>(expb, Ws, Wo_b, out);
}